// Round 1
// baseline (379.196 us; speedup 1.0000x reference)
//
#include <hip/hip_runtime.h>
#include <math.h>

#define BN 32
#define LL 1024
#define HH 128

typedef __attribute__((ext_vector_type(8))) short short8;
typedef __attribute__((ext_vector_type(4))) float f32x4;

static const size_t SZ_BF = (size_t)BN * LL * HH * 2;  // one bf16 matrix = 8 MB

__device__ __forceinline__ ushort f2bf(float x) {
  union { float f; unsigned u; } c; c.f = x;
  unsigned r = c.u + 0x7fffu + ((c.u >> 16) & 1u);
  return (ushort)(r >> 16);
}
__device__ __forceinline__ float bf2f(ushort h) {
  union { unsigned u; float f; } c; c.u = ((unsigned)h) << 16;
  return c.f;
}
__device__ __forceinline__ short8 ld8(const ushort* p) {
  return *(const short8*)p;
}

// ---------------------------------------------------------------------------
// k_convert: f32 -> bf16 copies of a,b plus transposed bf16 copies aT,bT.
// grid (16 l-tiles, 32 batches, 2 which), block 256.
// ---------------------------------------------------------------------------
__global__ __launch_bounds__(256) void k_convert(
    const float* __restrict__ a, const float* __restrict__ b,
    ushort* __restrict__ abf, ushort* __restrict__ bbf,
    ushort* __restrict__ aT, ushort* __restrict__ bT) {
  int bb = blockIdx.y;
  int l0 = blockIdx.x * 64;
  int which = blockIdx.z;
  const float* src = which ? b : a;
  ushort* dst  = which ? bbf : abf;
  ushort* dstT = which ? bT : aT;
  __shared__ __align__(16) ushort T[128][72];  // [d][l], padded
  int t = threadIdx.x;
  int lrow = t >> 5;         // 0..7
  int dcol = (t & 31) * 4;   // 0..124
#pragma unroll
  for (int p = 0; p < 8; ++p) {
    int l = p * 8 + lrow;
    float4 v = *(const float4*)&src[((size_t)bb * LL + l0 + l) * HH + dcol];
    ushort4 u;
    u.x = f2bf(v.x); u.y = f2bf(v.y); u.z = f2bf(v.z); u.w = f2bf(v.w);
    *(ushort4*)&dst[((size_t)bb * LL + l0 + l) * HH + dcol] = u;
    T[dcol + 0][l] = u.x; T[dcol + 1][l] = u.y;
    T[dcol + 2][l] = u.z; T[dcol + 3][l] = u.w;
  }
  __syncthreads();
  int drow = t >> 3;        // 0..31
  int c8 = (t & 7) * 8;     // 0..56
#pragma unroll
  for (int q = 0; q < 4; ++q) {
    int d = q * 32 + drow;
    short8 val = *(const short8*)&T[d][c8];
    *(short8*)&dstT[((size_t)bb * HH + d) * LL + l0 + c8] = val;
  }
}

// ---------------------------------------------------------------------------
// k_means: meanb[b][d] = sum_m b[b][m][d];  invmean[b][d] = sum_{m:mask_b=0} a
// grid (32 batches, 8 chunks, 2 which), block 256.  Outputs pre-zeroed.
// ---------------------------------------------------------------------------
__global__ __launch_bounds__(256) void k_means(
    const float* __restrict__ a, const float* __restrict__ b,
    const int* __restrict__ mask_b,
    float* __restrict__ meanb, float* __restrict__ invmean) {
  int bb = blockIdx.x;
  int c = blockIdx.y;
  int which = blockIdx.z;    // 0 -> meanb from b ; 1 -> invmean from a
  int t = threadIdx.x;
  int d = t & 127;
  int half = t >> 7;
  const float* src = which ? a : b;
  float acc = 0.f;
  for (int i = 0; i < 64; ++i) {
    int m = c * 128 + half * 64 + i;
    float w = 1.0f;
    if (which) w = (mask_b[bb * LL + m] == 0) ? 1.0f : 0.0f;
    acc += w * src[((size_t)bb * LL + m) * HH + d];
  }
  __shared__ float red[256];
  red[t] = acc;
  __syncthreads();
  if (t < 128) {
    float s = red[t] + red[t + 128];
    float* dstp = which ? invmean : meanb;
    atomicAdd(&dstp[bb * HH + d], s);
  }
}

// ---------------------------------------------------------------------------
// k_colsum: for each (b,m): colsum[m] = sum_l exp(s[l][m]*temp + biasA + biasB)
// Writes cc[b][m] = {inv_colsum (0 if colsum==0), biasB}.
// Orientation: A-operand = abf rows l (M-dim), B-operand = bbf rows m (N-dim)
// -> C col = m = per-lane constant -> in-register reduction.
// grid (16 m-tiles, 32 batches), block 256 (4 waves x 16 m each).
// ---------------------------------------------------------------------------
__global__ __launch_bounds__(256, 2) void k_colsum(
    const ushort* __restrict__ abf, const ushort* __restrict__ bbf,
    const int* __restrict__ mask_a, const int* __restrict__ mask_b,
    const float* __restrict__ temp_p, float2* __restrict__ cc) {
  int bb = blockIdx.y;
  int m0 = blockIdx.x * 64;
  int t = threadIdx.x;
  int w = t >> 6, lane = t & 63, l16 = lane & 15, quad = lane >> 4;
  float temp = temp_p[0];
  __shared__ float biasA[LL];
  for (int i = t; i < LL; i += 256)
    biasA[i] = mask_a[bb * LL + i] ? 0.0f : -10000.0f;
  __syncthreads();

  int m_lane = m0 + w * 16 + l16;
  float biasB = mask_b[bb * LL + m_lane] ? 0.0f : -10000.0f;

  short8 Bf[4];
  const ushort* brow = &bbf[((size_t)bb * LL + m_lane) * HH];
#pragma unroll
  for (int k = 0; k < 4; ++k) Bf[k] = ld8(&brow[k * 32 + quad * 8]);

  float cs = 0.f;
  for (int lit = 0; lit < 16; ++lit) {
    int lbase = lit * 64;
#pragma unroll
    for (int ts = 0; ts < 4; ++ts) {
      f32x4 acc = {0.f, 0.f, 0.f, 0.f};
      const ushort* arow = &abf[((size_t)bb * LL + lbase + ts * 16 + l16) * HH];
#pragma unroll
      for (int k = 0; k < 4; ++k) {
        short8 Af = ld8(&arow[k * 32 + quad * 8]);
        acc = __builtin_amdgcn_mfma_f32_16x16x32_bf16(Af, Bf[k], acc, 0, 0, 0);
      }
#pragma unroll
      for (int r = 0; r < 4; ++r) {
        int lr = lbase + ts * 16 + quad * 4 + r;
        cs += __expf(acc[r] * temp + biasA[lr] + biasB);
      }
    }
  }
  cs += __shfl_xor(cs, 16);
  cs += __shfl_xor(cs, 32);
  if (lane < 16) {
    float inv = cs > 0.f ? 1.0f / cs : 0.0f;
    cc[bb * LL + m_lane] = make_float2(inv, biasB);
  }
}

// ---------------------------------------------------------------------------
// k_features: per (b, 64-row l-block) sweep m-tiles of 64:
//   S' tile with M-dim=m, N-dim=l (C col = l); e = exp(s*temp+biasA+biasB);
//   rowsum accumulated in-register; P_a=e, P_b=e*inv_colsum written transposed
//   to wave-private LDS [l][m] (contiguous ds_write_b64), read back as A-frags;
//   feature_a += P_a @ bT, feature_b += P_b @ aT  (B-frags direct from global).
// Epilogue: fa = rowsum>0 ? acc/rowsum : mean(b);  fb = acc + invmean_a/1024.
// grid (16 l-blocks, 32 batches), block 256.
// ---------------------------------------------------------------------------
__global__ __launch_bounds__(256, 2) void k_features(
    const ushort* __restrict__ abf, const ushort* __restrict__ bbf,
    const ushort* __restrict__ aT, const ushort* __restrict__ bT,
    const int* __restrict__ mask_a, const float* __restrict__ temp_p,
    const float2* __restrict__ cc, const float* __restrict__ meanb,
    const float* __restrict__ invmean, float* __restrict__ out) {
  int bb = blockIdx.y;
  int l0 = blockIdx.x * 64;
  int t = threadIdx.x;
  int w = t >> 6, lane = t & 63, l16 = lane & 15, quad = lane >> 4;
  float temp = temp_p[0];

  __shared__ float2 ccs[LL];                      // 8 KB: {inv_colsum, biasB}
  __shared__ __align__(16) ushort Pa[4][16 * 72]; // wave-private P buffers
  __shared__ __align__(16) ushort Pb[4][16 * 72];
  __shared__ float rsbuf[4][16];

  for (int i = t; i < LL; i += 256) ccs[i] = cc[bb * LL + i];
  __syncthreads();

  int l_lane = l0 + w * 16 + l16;
  float biasA = mask_a[bb * LL + l_lane] ? 0.0f : -10000.0f;

  // fixed B-operand (abf rows = wave's 16 l's), K=128 -> 4 frags in registers
  short8 Afix[4];
  const ushort* arow = &abf[((size_t)bb * LL + l_lane) * HH];
#pragma unroll
  for (int k = 0; k < 4; ++k) Afix[k] = ld8(&arow[k * 32 + quad * 8]);

  f32x4 accA[8], accB[8];
  f32x4 zero = {0.f, 0.f, 0.f, 0.f};
#pragma unroll
  for (int i = 0; i < 8; ++i) { accA[i] = zero; accB[i] = zero; }
  float rs = 0.f;
  ushort* pa = &Pa[w][0];
  ushort* pb = &Pb[w][0];

  for (int m0 = 0; m0 < LL; m0 += 64) {
#pragma unroll
    for (int ts = 0; ts < 4; ++ts) {
      f32x4 acc = zero;
      const ushort* brow = &bbf[((size_t)bb * LL + m0 + ts * 16 + l16) * HH];
#pragma unroll
      for (int k = 0; k < 4; ++k) {
        short8 Mf = ld8(&brow[k * 32 + quad * 8]);   // A-operand: rows m
        acc = __builtin_amdgcn_mfma_f32_16x16x32_bf16(Mf, Afix[k], acc, 0, 0, 0);
      }
      ushort pav[4], pbv[4];
#pragma unroll
      for (int r = 0; r < 4; ++r) {
        int m = m0 + ts * 16 + quad * 4 + r;
        float2 cv = ccs[m];
        float e = __expf(acc[r] * temp + biasA + cv.y);
        pav[r] = f2bf(e);
        rs += bf2f(pav[r]);           // rounded value -> cancels in fa=acc/rs
        pbv[r] = f2bf(e * cv.x);
      }
      uint2 ka, kb;
      ka.x = (uint)pav[0] | ((uint)pav[1] << 16);
      ka.y = (uint)pav[2] | ((uint)pav[3] << 16);
      kb.x = (uint)pbv[0] | ((uint)pbv[1] << 16);
      kb.y = (uint)pbv[2] | ((uint)pbv[3] << 16);
      *(uint2*)&pa[l16 * 72 + ts * 16 + quad * 4] = ka;
      *(uint2*)&pb[l16 * 72 + ts * 16 + quad * 4] = kb;
    }
    // P A-frags (rows = wave's l's, K = m)
    short8 PaF[2], PbF[2];
#pragma unroll
    for (int ks = 0; ks < 2; ++ks) {
      PaF[ks] = *(const short8*)&pa[l16 * 72 + ks * 32 + quad * 8];
      PbF[ks] = *(const short8*)&pb[l16 * 72 + ks * 32 + quad * 8];
    }
#pragma unroll
    for (int ds = 0; ds < 8; ++ds) {
      const ushort* btrow = &bT[((size_t)bb * HH + ds * 16 + l16) * LL + m0];
      const ushort* atrow = &aT[((size_t)bb * HH + ds * 16 + l16) * LL + m0];
#pragma unroll
      for (int ks = 0; ks < 2; ++ks) {
        short8 Bb = ld8(&btrow[ks * 32 + quad * 8]);
        accA[ds] = __builtin_amdgcn_mfma_f32_16x16x32_bf16(PaF[ks], Bb, accA[ds], 0, 0, 0);
        short8 Ba = ld8(&atrow[ks * 32 + quad * 8]);
        accB[ds] = __builtin_amdgcn_mfma_f32_16x16x32_bf16(PbF[ks], Ba, accB[ds], 0, 0, 0);
      }
    }
  }

  rs += __shfl_xor(rs, 16);
  rs += __shfl_xor(rs, 32);
  if (lane < 16) rsbuf[w][l16] = rs;
  __syncthreads();

  float* outA = out;
  float* outB = out + (size_t)BN * LL * HH;
#pragma unroll
  for (int ds = 0; ds < 8; ++ds) {
    int d = ds * 16 + l16;
    float mb = meanb[bb * HH + d] * (1.0f / 1024.0f);
    float im = invmean[bb * HH + d] * (1.0f / 1024.0f);
#pragma unroll
    for (int r = 0; r < 4; ++r) {
      int l = l0 + w * 16 + quad * 4 + r;
      float rsv = rsbuf[w][quad * 4 + r];
      float fa = (rsv > 0.f) ? accA[ds][r] / rsv : mb;
      float fb = accB[ds][r] + im;
      outA[((size_t)bb * LL + l) * HH + d] = fa;
      outB[((size_t)bb * LL + l) * HH + d] = fb;
    }
  }
}

// ---------------------------------------------------------------------------
extern "C" void kernel_launch(void* const* d_in, const int* in_sizes, int n_in,
                              void* d_out, int out_size, void* d_ws, size_t ws_size,
                              hipStream_t stream) {
  const float* a = (const float*)d_in[0];
  const float* b = (const float*)d_in[1];
  const int* mask_a = (const int*)d_in[2];
  const int* mask_b = (const int*)d_in[3];
  const float* temp = (const float*)d_in[4];
  float* out = (float*)d_out;

  char* wsb = (char*)d_ws;
  ushort* abf = (ushort*)(wsb + 0 * SZ_BF);
  ushort* bbf = (ushort*)(wsb + 1 * SZ_BF);
  ushort* aT  = (ushort*)(wsb + 2 * SZ_BF);
  ushort* bT  = (ushort*)(wsb + 3 * SZ_BF);
  float2* cc  = (float2*)(wsb + 4 * SZ_BF);
  float* meanb   = (float*)(wsb + 4 * SZ_BF + (size_t)BN * LL * sizeof(float2));
  float* invmean = meanb + BN * HH;

  hipMemsetAsync(meanb, 0, 2 * BN * HH * sizeof(float), stream);
  k_convert<<<dim3(16, 32, 2), 256, 0, stream>>>(a, b, abf, bbf, aT, bT);
  k_means<<<dim3(32, 8, 2), 256, 0, stream>>>(a, b, mask_b, meanb, invmean);
  k_colsum<<<dim3(16, 32), 256, 0, stream>>>(abf, bbf, mask_a, mask_b, temp, cc);
  k_features<<<dim3(16, 32), 256, 0, stream>>>(abf, bbf, aT, bT, mask_a, temp,
                                               cc, meanb, invmean, out);
  (void)in_sizes; (void)n_in; (void)out_size; (void)ws_size;
}

// Round 2
// 181.568 us; speedup vs baseline: 2.0885x; 2.0885x over previous
//
#include <hip/hip_runtime.h>
#include <math.h>

#define BN 32
#define LL 1024
#define HH 128

typedef __attribute__((ext_vector_type(8))) short short8;
typedef __attribute__((ext_vector_type(4))) float f32x4;

static const size_t SZ_BF = (size_t)BN * LL * HH * 2;  // one bf16 matrix = 8 MB

__device__ __forceinline__ ushort f2bf(float x) {
  union { float f; unsigned u; } c; c.f = x;
  unsigned r = c.u + 0x7fffu + ((c.u >> 16) & 1u);
  return (ushort)(r >> 16);
}
__device__ __forceinline__ float bf2f(ushort h) {
  union { unsigned u; float f; } c; c.u = ((unsigned)h) << 16;
  return c.f;
}
__device__ __forceinline__ short8 ld8(const ushort* p) {
  return *(const short8*)p;
}

// ---------------------------------------------------------------------------
// k_convert: f32 -> bf16 copies of a,b plus transposed bf16 copies aT,bT.
// Fused: meanb[b][d] = sum_m b[m][d]; invmean[b][d] = sum_{m:mask_b=0} a[m][d]
// (accumulated via the transpose LDS tile -> LDS atomic -> 1 global atomic).
// grid (16 l-tiles, 32 batches, 2 which), block 256.
// ---------------------------------------------------------------------------
__global__ __launch_bounds__(256) void k_convert(
    const float* __restrict__ a, const float* __restrict__ b,
    const int* __restrict__ mask_b,
    ushort* __restrict__ abf, ushort* __restrict__ bbf,
    ushort* __restrict__ aT, ushort* __restrict__ bT,
    float* __restrict__ meanb, float* __restrict__ invmean) {
  int bb = blockIdx.y;
  int l0 = blockIdx.x * 64;
  int which = blockIdx.z;              // 0 -> a (->invmean), 1 -> b (->meanb)
  const float* src = which ? b : a;
  ushort* dst  = which ? bbf : abf;
  ushort* dstT = which ? bT : aT;
  float* dmean = which ? meanb : invmean;
  __shared__ __align__(16) ushort T[128][72];  // [d][l], padded
  __shared__ float accS[128];
  __shared__ float wgt[64];
  int t = threadIdx.x;
  if (t < 128) accS[t] = 0.f;
  if (t < 64)
    wgt[t] = which ? 1.0f : ((mask_b[bb * LL + l0 + t] == 0) ? 1.0f : 0.0f);
  int lrow = t >> 5;         // 0..7
  int dcol = (t & 31) * 4;   // 0..124
#pragma unroll
  for (int p = 0; p < 8; ++p) {
    int l = p * 8 + lrow;
    float4 v = *(const float4*)&src[((size_t)bb * LL + l0 + l) * HH + dcol];
    ushort4 u;
    u.x = f2bf(v.x); u.y = f2bf(v.y); u.z = f2bf(v.z); u.w = f2bf(v.w);
    *(ushort4*)&dst[((size_t)bb * LL + l0 + l) * HH + dcol] = u;
    T[dcol + 0][l] = u.x; T[dcol + 1][l] = u.y;
    T[dcol + 2][l] = u.z; T[dcol + 3][l] = u.w;
  }
  __syncthreads();
  int drow = t >> 3;        // 0..31
  int c8 = (t & 7) * 8;     // 0..56
#pragma unroll
  for (int q = 0; q < 4; ++q) {
    int d = q * 32 + drow;
    short8 val = *(const short8*)&T[d][c8];
    *(short8*)&dstT[((size_t)bb * HH + d) * LL + l0 + c8] = val;
    float s = 0.f;
#pragma unroll
    for (int j = 0; j < 8; ++j) s += wgt[c8 + j] * bf2f((ushort)val[j]);
    atomicAdd(&accS[d], s);
  }
  __syncthreads();
  if (t < 128) atomicAdd(&dmean[bb * HH + t], accS[t]);
}

// ---------------------------------------------------------------------------
// k_colsum: colsum[m] = sum_l exp(s[l][m]*temp + biasA[l] + biasB[m]).
// Block covers 64 m (all l); wave w sweeps l-quarter w*256.. (no duplicated
// loads). B-frags (bbf rows m) fixed in regs; cross-wave reduce via LDS.
// Writes cc[b][m] = {inv_colsum (0 if colsum==0), biasB}.
// grid (16 m-tiles, 32 batches), block 256.
// ---------------------------------------------------------------------------
__global__ __launch_bounds__(256, 2) void k_colsum(
    const ushort* __restrict__ abf, const ushort* __restrict__ bbf,
    const int* __restrict__ mask_a, const int* __restrict__ mask_b,
    const float* __restrict__ temp_p, float2* __restrict__ cc) {
  int bb = blockIdx.y;
  int m0 = blockIdx.x * 64;
  int t = threadIdx.x;
  int w = t >> 6, lane = t & 63, l16 = lane & 15, quad = lane >> 4;
  float temp = temp_p[0];
  __shared__ float biasA[LL];
  __shared__ float csred[4][4][16];
  for (int i = t; i < LL; i += 256)
    biasA[i] = mask_a[bb * LL + i] ? 0.0f : -10000.0f;

  short8 Bm[4][4];
  float biasB_mt[4];
#pragma unroll
  for (int mt = 0; mt < 4; ++mt) {
    int m = m0 + mt * 16 + l16;
    biasB_mt[mt] = mask_b[bb * LL + m] ? 0.0f : -10000.0f;
#pragma unroll
    for (int k = 0; k < 4; ++k)
      Bm[mt][k] = ld8(&bbf[((size_t)bb * LL + m) * HH + k * 32 + quad * 8]);
  }
  __syncthreads();

  float cs[4] = {0.f, 0.f, 0.f, 0.f};
  for (int it = 0; it < 16; ++it) {
    int lbase = w * 256 + it * 16;
    short8 Al[4];
    const ushort* arow = &abf[((size_t)bb * LL + lbase + l16) * HH];
#pragma unroll
    for (int k = 0; k < 4; ++k) Al[k] = ld8(&arow[k * 32 + quad * 8]);
#pragma unroll
    for (int mt = 0; mt < 4; ++mt) {
      f32x4 sacc = {0.f, 0.f, 0.f, 0.f};
#pragma unroll
      for (int k = 0; k < 4; ++k)
        sacc = __builtin_amdgcn_mfma_f32_16x16x32_bf16(Al[k], Bm[mt][k], sacc, 0, 0, 0);
#pragma unroll
      for (int r = 0; r < 4; ++r) {
        int l = lbase + quad * 4 + r;   // D row = l; col = m = mt*16+l16
        cs[mt] += __expf(sacc[r] * temp + biasA[l] + biasB_mt[mt]);
      }
    }
  }
#pragma unroll
  for (int mt = 0; mt < 4; ++mt) {
    cs[mt] += __shfl_xor(cs[mt], 16);
    cs[mt] += __shfl_xor(cs[mt], 32);
  }
  if (lane < 16) {
#pragma unroll
    for (int mt = 0; mt < 4; ++mt) csred[w][mt][l16] = cs[mt];
  }
  __syncthreads();
  if (t < 64) {
    int mt = t >> 4, ml = t & 15;
    float s = csred[0][mt][ml] + csred[1][mt][ml] + csred[2][mt][ml] + csred[3][mt][ml];
    int m = m0 + t;
    float bB = mask_b[bb * LL + m] ? 0.0f : -10000.0f;
    cc[bb * LL + m] = make_float2(s > 0.f ? 1.0f / s : 0.0f, bB);
  }
}

// ---------------------------------------------------------------------------
// k_features: block = 64 l-rows x full m-sweep x all 128 d.
//   S-phase:  wave w computes S'[m-slice w (16m)][all 64 l] (abf B-frags fixed
//             in regs, bbf A-frags 4 loads/iter, no cross-wave duplication);
//             e = exp(s*temp+biasA+biasB); Pa=e, Pb=e*inv_colsum -> LDS
//             P[l][m] (double-buffered, ONE barrier per iter).
//   F-phase:  wave w owns d-slice w*32 (32 of 128 d): feature_a += Pa @ bT,
//             feature_b += Pb @ aT; aT/bT B-frags direct from global
//             (8 loads/iter, no duplication), Pa/Pb A-frags via ds_read_b128.
// Epilogue: fa = rowsum>0 ? acc/rowsum : mean(b); fb = acc + invmean_a/1024.
// grid (16 l-blocks, 32 batches), block 256.
// ---------------------------------------------------------------------------
__global__ __launch_bounds__(256, 2) void k_features(
    const ushort* __restrict__ abf, const ushort* __restrict__ bbf,
    const ushort* __restrict__ aT, const ushort* __restrict__ bT,
    const int* __restrict__ mask_a, const float* __restrict__ temp_p,
    const float2* __restrict__ cc, const float* __restrict__ meanb,
    const float* __restrict__ invmean, float* __restrict__ out) {
  int bb = blockIdx.y;
  int l0 = blockIdx.x * 64;
  int t = threadIdx.x;
  int w = t >> 6, lane = t & 63, l16 = lane & 15, quad = lane >> 4;
  float temp = temp_p[0];

  __shared__ float2 ccs[LL];                        // 8 KB
  __shared__ __align__(16) ushort Pa[2][64 * 72];   // double-buffered, 18.4 KB
  __shared__ __align__(16) ushort Pb[2][64 * 72];   // 18.4 KB
  __shared__ float rspart[4][64];
  __shared__ float rsfin[64];

  for (int i = t; i < LL; i += 256) ccs[i] = cc[bb * LL + i];

  float biasA_lt[4];
  short8 Afix[4][4];   // abf rows l0..l0+63 as B-operands (64 VGPRs)
#pragma unroll
  for (int lt = 0; lt < 4; ++lt) {
    int l = l0 + lt * 16 + l16;
    biasA_lt[lt] = mask_a[bb * LL + l] ? 0.0f : -10000.0f;
#pragma unroll
    for (int k = 0; k < 4; ++k)
      Afix[lt][k] = ld8(&abf[((size_t)bb * LL + l) * HH + k * 32 + quad * 8]);
  }

  f32x4 accA[4][2], accB[4][2];
  f32x4 zero = {0.f, 0.f, 0.f, 0.f};
#pragma unroll
  for (int lt = 0; lt < 4; ++lt)
#pragma unroll
    for (int dt = 0; dt < 2; ++dt) { accA[lt][dt] = zero; accB[lt][dt] = zero; }
  float rs_lt[4] = {0.f, 0.f, 0.f, 0.f};
  __syncthreads();   // ccs ready

  int buf = 0;
  for (int m0 = 0; m0 < LL; m0 += 64) {
    // ---- global loads for this iter (issued up front) ----
    short8 Am[4];
    const ushort* brow = &bbf[((size_t)bb * LL + m0 + w * 16 + l16) * HH];
#pragma unroll
    for (int k = 0; k < 4; ++k) Am[k] = ld8(&brow[k * 32 + quad * 8]);
    short8 Bb[2][2], Ba[2][2];
#pragma unroll
    for (int dt = 0; dt < 2; ++dt) {
      const ushort* btrow = &bT[((size_t)bb * HH + w * 32 + dt * 16 + l16) * LL + m0];
      const ushort* atrow = &aT[((size_t)bb * HH + w * 32 + dt * 16 + l16) * LL + m0];
#pragma unroll
      for (int ks = 0; ks < 2; ++ks) {
        Bb[dt][ks] = ld8(&btrow[ks * 32 + quad * 8]);
        Ba[dt][ks] = ld8(&atrow[ks * 32 + quad * 8]);
      }
    }
    float2 cv[4];
#pragma unroll
    for (int r = 0; r < 4; ++r) cv[r] = ccs[m0 + w * 16 + quad * 4 + r];

    // ---- S-phase: D[m=w*16+quad*4+r][l=lt*16+l16] ----
    ushort* pa = &Pa[buf][0];
    ushort* pb = &Pb[buf][0];
#pragma unroll
    for (int lt = 0; lt < 4; ++lt) {
      f32x4 sacc = zero;
#pragma unroll
      for (int k = 0; k < 4; ++k)
        sacc = __builtin_amdgcn_mfma_f32_16x16x32_bf16(Am[k], Afix[lt][k], sacc, 0, 0, 0);
      ushort pav[4], pbv[4];
#pragma unroll
      for (int r = 0; r < 4; ++r) {
        float e = __expf(sacc[r] * temp + biasA_lt[lt] + cv[r].y);
        pav[r] = f2bf(e);
        rs_lt[lt] += bf2f(pav[r]);     // rounded value -> cancels in fa=acc/rs
        pbv[r] = f2bf(e * cv[r].x);
      }
      uint2 ka, kb;
      ka.x = (uint)pav[0] | ((uint)pav[1] << 16);
      ka.y = (uint)pav[2] | ((uint)pav[3] << 16);
      kb.x = (uint)pbv[0] | ((uint)pbv[1] << 16);
      kb.y = (uint)pbv[2] | ((uint)pbv[3] << 16);
      int pidx = (lt * 16 + l16) * 72 + w * 16 + quad * 4;
      *(uint2*)&pa[pidx] = ka;
      *(uint2*)&pb[pidx] = kb;
    }
    __syncthreads();   // P[buf] complete (prev buf still readable -> 1 barrier)

    // ---- F-phase: D[l=lt*16+quad*4+r][d=w*32+dt*16+l16] ----
#pragma unroll
    for (int lt = 0; lt < 4; ++lt) {
#pragma unroll
      for (int ks = 0; ks < 2; ++ks) {
        int ridx = (lt * 16 + l16) * 72 + ks * 32 + quad * 8;
        short8 PaF = *(const short8*)&pa[ridx];
        short8 PbF = *(const short8*)&pb[ridx];
#pragma unroll
        for (int dt = 0; dt < 2; ++dt) {
          accA[lt][dt] = __builtin_amdgcn_mfma_f32_16x16x32_bf16(PaF, Bb[dt][ks], accA[lt][dt], 0, 0, 0);
          accB[lt][dt] = __builtin_amdgcn_mfma_f32_16x16x32_bf16(PbF, Ba[dt][ks], accB[lt][dt], 0, 0, 0);
        }
      }
    }
    buf ^= 1;
  }

  // ---- rowsum cross-wave reduce ----
#pragma unroll
  for (int lt = 0; lt < 4; ++lt) {
    rs_lt[lt] += __shfl_xor(rs_lt[lt], 16);
    rs_lt[lt] += __shfl_xor(rs_lt[lt], 32);
  }
  if (lane < 16) {
#pragma unroll
    for (int lt = 0; lt < 4; ++lt) rspart[w][lt * 16 + l16] = rs_lt[lt];
  }
  __syncthreads();
  if (t < 64)
    rsfin[t] = rspart[0][t] + rspart[1][t] + rspart[2][t] + rspart[3][t];
  __syncthreads();

  // ---- epilogue ----
  float* outA = out;
  float* outB = out + (size_t)BN * LL * HH;
#pragma unroll
  for (int dt = 0; dt < 2; ++dt) {
    int d = w * 32 + dt * 16 + l16;
    float mb = meanb[bb * HH + d] * (1.0f / 1024.0f);
    float im = invmean[bb * HH + d] * (1.0f / 1024.0f);
#pragma unroll
    for (int lt = 0; lt < 4; ++lt) {
#pragma unroll
      for (int r = 0; r < 4; ++r) {
        int l = lt * 16 + quad * 4 + r;
        float rsv = rsfin[l];
        float fa = (rsv > 0.f) ? accA[lt][dt][r] / rsv : mb;
        float fb = accB[lt][dt][r] + im;
        outA[((size_t)bb * LL + l0 + l) * HH + d] = fa;
        outB[((size_t)bb * LL + l0 + l) * HH + d] = fb;
      }
    }
  }
}

// ---------------------------------------------------------------------------
extern "C" void kernel_launch(void* const* d_in, const int* in_sizes, int n_in,
                              void* d_out, int out_size, void* d_ws, size_t ws_size,
                              hipStream_t stream) {
  const float* a = (const float*)d_in[0];
  const float* b = (const float*)d_in[1];
  const int* mask_a = (const int*)d_in[2];
  const int* mask_b = (const int*)d_in[3];
  const float* temp = (const float*)d_in[4];
  float* out = (float*)d_out;

  char* wsb = (char*)d_ws;
  ushort* abf = (ushort*)(wsb + 0 * SZ_BF);
  ushort* bbf = (ushort*)(wsb + 1 * SZ_BF);
  ushort* aT  = (ushort*)(wsb + 2 * SZ_BF);
  ushort* bT  = (ushort*)(wsb + 3 * SZ_BF);
  float2* cc  = (float2*)(wsb + 4 * SZ_BF);
  float* meanb   = (float*)(wsb + 4 * SZ_BF + (size_t)BN * LL * sizeof(float2));
  float* invmean = meanb + BN * HH;

  hipMemsetAsync(meanb, 0, 2 * BN * HH * sizeof(float), stream);
  k_convert<<<dim3(16, 32, 2), 256, 0, stream>>>(a, b, mask_b, abf, bbf, aT, bT,
                                                 meanb, invmean);
  k_colsum<<<dim3(16, 32), 256, 0, stream>>>(abf, bbf, mask_a, mask_b, temp, cc);
  k_features<<<dim3(16, 32), 256, 0, stream>>>(abf, bbf, aT, bT, mask_a, temp,
                                               cc, meanb, invmean, out);
  (void)in_sizes; (void)n_in; (void)out_size; (void)ws_size;
}